// Round 4
// baseline (303.593 us; speedup 1.0000x reference)
//
#include <hip/hip_runtime.h>

#define NSRC 50000
#define NDST 10000
#define NEDGE 250000
#define NREL 4
#define NEG_SLOPE 0.2f

typedef unsigned short u16;
typedef __attribute__((ext_vector_type(8))) short bf16x8;
typedef __attribute__((ext_vector_type(4))) float f32x4;

#define GLD16(g, l) __builtin_amdgcn_global_load_lds( \
    (__attribute__((address_space(1))) void*)(void*)(g), \
    (__attribute__((address_space(3))) void*)(l), 16, 0, 0)

static __device__ __forceinline__ u16 f2b(float f) {
  unsigned u = __float_as_uint(f);
  unsigned r = (u + 0x7FFFu + ((u >> 16) & 1u)) >> 16;
  return (u16)r;
}
static __device__ __forceinline__ float b2f(u16 b) {
  return __uint_as_float((unsigned)b << 16);
}
static __device__ __forceinline__ float leaky(float x) {
  return x > 0.f ? x : NEG_SLOPE * x;
}

// ---------------- conversions ----------------
__global__ __launch_bounds__(256) void cvtx_k(const float* __restrict__ x,
                                              u16* __restrict__ xb) {
  int i = blockIdx.x * 256 + threadIdx.x;  // group of 4 elements
  float4 v = ((const float4*)x)[i];
  uint2 o;
  o.x = (unsigned)f2b(v.x) | ((unsigned)f2b(v.y) << 16);
  o.y = (unsigned)f2b(v.z) | ((unsigned)f2b(v.w) << 16);
  ((uint2*)xb)[i] = o;
}

// Wt rows 0..1023: W[r][k][n] n-major; rows 1024..1279: loop_w
__global__ __launch_bounds__(256) void cvtw_k(const float* __restrict__ W,
                                              const float* __restrict__ loop_w,
                                              u16* __restrict__ Wt) {
  int row = blockIdx.x;        // 0..1279
  int k = threadIdx.x;         // 0..255
  int mat = row >> 8, c = row & 255;
  float v = (mat < 4) ? W[(size_t)mat * 65536 + (size_t)k * 256 + c]
                      : loop_w[(size_t)k * 256 + c];
  Wt[(size_t)row * 256 + k] = f2b(v);
}

// Wt rows 1280..1407 (base passed in): c<16 el = W[r]@attn_l; 16..31 er; >=32 zero
__global__ __launch_bounds__(256) void wa_k(const float* __restrict__ W,
                                            const float* __restrict__ al,
                                            const float* __restrict__ ar,
                                            u16* __restrict__ WAt) {
  int g = blockIdx.x * 256 + threadIdx.x;  // 0..32767
  int c = g >> 8, k = g & 255;
  float acc = 0.f;
  if (c < 32) {
    int cc = c & 15;
    int r = cc >> 2, h = cc & 3;
    const float* vec = ((c < 16) ? al : ar) + r * 256 + h * 64;
    const float* wrow = W + (size_t)r * 65536 + (size_t)k * 256 + h * 64;
    #pragma unroll 8
    for (int j = 0; j < 64; ++j) acc += wrow[j] * vec[j];
  }
  WAt[(size_t)c * 256 + k] = f2b(acc);
}

// ---------------- fused GEMM: [hb | loopo | elr] = xb @ Wt^T ----------------
// B n-major [1408][256]. Tile 128x128, BK=64, 4 waves (2x2 of 64x64).
// cols <1024 -> hb bf16; 1024..1279 -> loopo bf16 (rows<NDST); 1280..1311 -> elr f32
__global__ __launch_bounds__(256) void gemm_k(const u16* __restrict__ A,
                                              const u16* __restrict__ B,
                                              u16* __restrict__ hb,
                                              u16* __restrict__ loopo,
                                              float* __restrict__ elr) {
  __shared__ u16 As[128 * 64];
  __shared__ u16 Bs[128 * 64];
  const int tid = threadIdx.x;
  const int w = tid >> 6, l = tid & 63;
  const int bm = blockIdx.y * 128, bn = blockIdx.x * 128;
  const int wm = (w >> 1) * 64, wn = (w & 1) * 64;
  f32x4 acc[4][4] = {};
  const int lrow = l >> 3, lchunk = l & 7;

  for (int t = 0; t < 4; ++t) {
    const int k0 = t * 64;
    #pragma unroll
    for (int c = 0; c < 4; ++c) {
      int rb = (w * 4 + c) * 8;
      int row_in = rb + lrow;
      int colb = (lchunk * 16) ^ ((row_in & 7) << 4);
      long arow = bm + row_in;
      if (arow >= NSRC) arow = NSRC - 1;
      const char* ga = (const char*)A + ((size_t)arow * 256 + k0) * 2 + colb;
      GLD16(ga, (char*)As + rb * 128);
      const char* gb = (const char*)B + ((size_t)(bn + row_in) * 256 + k0) * 2 + colb;
      GLD16(gb, (char*)Bs + rb * 128);
    }
    __syncthreads();
    #pragma unroll
    for (int kk = 0; kk < 2; ++kk) {
      bf16x8 af[4], bg[4];
      #pragma unroll
      for (int m = 0; m < 4; ++m) {
        int row = wm + m * 16 + (l & 15);
        int colb = (kk * 64 + ((l >> 4) * 16)) ^ ((row & 7) << 4);
        af[m] = *(const bf16x8*)((const char*)As + row * 128 + colb);
      }
      #pragma unroll
      for (int n = 0; n < 4; ++n) {
        int row = wn + n * 16 + (l & 15);
        int colb = (kk * 64 + ((l >> 4) * 16)) ^ ((row & 7) << 4);
        bg[n] = *(const bf16x8*)((const char*)Bs + row * 128 + colb);
      }
      #pragma unroll
      for (int m = 0; m < 4; ++m)
        #pragma unroll
        for (int n = 0; n < 4; ++n)
          acc[m][n] = __builtin_amdgcn_mfma_f32_16x16x32_bf16(af[m], bg[n], acc[m][n], 0, 0, 0);
    }
    __syncthreads();
  }
  #pragma unroll
  for (int m = 0; m < 4; ++m) {
    #pragma unroll
    for (int j = 0; j < 4; ++j) {
      int row = bm + wm + m * 16 + (l >> 4) * 4 + j;
      if (row < NSRC) {
        #pragma unroll
        for (int n = 0; n < 4; ++n) {
          int col = bn + wn + n * 16 + (l & 15);
          float v = acc[m][n][j];
          if (col < 1024) {
            hb[(size_t)row * 1024 + col] = f2b(v);
          } else if (col < 1280) {
            if (row < NDST) loopo[(size_t)row * 256 + (col - 1024)] = f2b(v);
          } else if (col < 1312) {
            elr[(size_t)row * 32 + (col - 1280)] = v;
          }
        }
      }
    }
  }
}

// ---------------- CSR build (all 4 relations at once) ----------------
__global__ void hist_k(const int* __restrict__ edst, int* __restrict__ counts) {
  int g = blockIdx.x * 256 + threadIdx.x;
  if (g >= NREL * NEDGE) return;
  int r = g / NEDGE;
  atomicAdd(&counts[r * NDST + edst[g]], 1);
}

__global__ __launch_bounds__(1024) void scanA_k(const int* __restrict__ counts,
                                                int* __restrict__ offsets,
                                                int* __restrict__ btot) {
  __shared__ int wsum[16];
  int tid = threadIdx.x, lane = tid & 63, wid = tid >> 6;
  int i = blockIdx.x * 1024 + tid;
  int v = (i < NREL * NDST) ? counts[i] : 0;
  int x = v;
  #pragma unroll
  for (int off = 1; off < 64; off <<= 1) {
    int t = __shfl_up(x, off);
    if (lane >= off) x += t;
  }
  if (lane == 63) wsum[wid] = x;
  __syncthreads();
  if (wid == 0) {
    int t = (lane < 16) ? wsum[lane] : 0;
    #pragma unroll
    for (int off = 1; off < 16; off <<= 1) {
      int u = __shfl_up(t, off);
      if (lane >= off) t += u;
    }
    if (lane < 16) wsum[lane] = t;
  }
  __syncthreads();
  int wpre = (wid > 0) ? wsum[wid - 1] : 0;
  int incl = x + wpre;
  if (i < NREL * NDST) offsets[i] = incl - v;
  if (tid == 1023) btot[blockIdx.x] = incl;
}

__global__ void scanB_k(const int* __restrict__ btot, int* __restrict__ carry) {
  int lane = threadIdx.x;  // 64 threads = 1 wave
  int v = (lane < 40) ? btot[lane] : 0;
  int x = v;
  #pragma unroll
  for (int off = 1; off < 64; off <<= 1) {
    int t = __shfl_up(x, off);
    if (lane >= off) x += t;
  }
  if (lane < 40) carry[lane] = x - v;
}

__global__ __launch_bounds__(1024) void scanC_k(int* __restrict__ offsets,
                                                const int* __restrict__ carry,
                                                int* __restrict__ cursor) {
  int i = blockIdx.x * 1024 + threadIdx.x;
  if (i < NREL * NDST) {
    int o = offsets[i] + carry[blockIdx.x];
    offsets[i] = o;
    cursor[i] = o;
  }
  if (i == 0) offsets[NREL * NDST] = NREL * NEDGE;
}

__global__ void scatter_k(const int* __restrict__ esrc, const int* __restrict__ edst,
                          int* __restrict__ cursor, int* __restrict__ perm_src) {
  int g = blockIdx.x * 256 + threadIdx.x;
  if (g >= NREL * NEDGE) return;
  int r = g / NEDGE;
  int pos = atomicAdd(&cursor[r * NDST + edst[g]], 1);
  perm_src[pos] = esrc[g];
}

// ---------------- fused softmax + aggregate + output ----------------
// Block = one dst (512 threads, 8 waves). Wave w: relation r=w&3, pair p=w>>2.
// Softmax without max-subtraction (|e| small, exp safe in f32, shift-invariant).
// Gather: half-wave (32 lanes x 16B = 512B/edge), 4 streams/rel, 2-edge unroll.
__global__ __launch_bounds__(512) void agg_k(const u16* __restrict__ hb,
                                             const int* __restrict__ offs,
                                             const int* __restrict__ perm,
                                             const float* __restrict__ elr,
                                             const u16* __restrict__ loopo,
                                             const float* __restrict__ loop_b,
                                             float* __restrict__ out) {
  __shared__ float sacc[8][256];
  __shared__ float ssum[8][4];
  const int d = blockIdx.x;
  const int tid = threadIdx.x;
  const int w = tid >> 6, lane = tid & 63;
  const int r = w & 3, p = w >> 2;
  const int seg = r * NDST + d;
  const int beg = offs[seg], end = offs[seg + 1];
  const float4 r4 = *(const float4*)(elr + (size_t)d * 32 + 16 + r * 4);

  // phase A: denom_h = sum over edges of exp(leaky(el_h + er_h))
  float s0 = 0.f, s1 = 0.f, s2 = 0.f, s3 = 0.f;
  for (int i = beg + p * 64 + lane; i < end; i += 128) {
    int s = perm[i];
    float4 l4 = *(const float4*)(elr + (size_t)s * 32 + r * 4);
    s0 += __expf(leaky(l4.x + r4.x));
    s1 += __expf(leaky(l4.y + r4.y));
    s2 += __expf(leaky(l4.z + r4.z));
    s3 += __expf(leaky(l4.w + r4.w));
  }
  #pragma unroll
  for (int off = 1; off < 64; off <<= 1) {
    s0 += __shfl_xor(s0, off);
    s1 += __shfl_xor(s1, off);
    s2 += __shfl_xor(s2, off);
    s3 += __shfl_xor(s3, off);
  }
  if (lane == 0) {
    ssum[w][0] = s0; ssum[w][1] = s1; ssum[w][2] = s2; ssum[w][3] = s3;
  }
  __syncthreads();

  // phase B: out_ch += alpha_e * h[src_e][ch], half-wave per edge, 2-edge unroll
  const int lane32 = lane & 31;
  const int hw = p * 2 + (lane >> 5);
  const int head = lane32 >> 3;
  const float r4h = head == 0 ? r4.x : head == 1 ? r4.y : head == 2 ? r4.z : r4.w;
  const float dsum = ssum[r][head] + ssum[r + 4][head];
  const float rd = 1.f / fmaxf(dsum, 1e-9f);
  const int r4i = r * 4 + head;
  const size_t hoff = (size_t)r * 256 + lane32 * 8;
  float a0 = 0.f, a1 = 0.f, a2 = 0.f, a3 = 0.f;
  float a4 = 0.f, a5 = 0.f, a6 = 0.f, a7 = 0.f;
  int i = beg + hw;
  for (; i + 4 < end; i += 8) {
    int sA = perm[i];
    int sB = perm[i + 4];
    float eA = elr[(size_t)sA * 32 + r4i];
    float eB = elr[(size_t)sB * 32 + r4i];
    uint4 hA = *(const uint4*)(hb + (size_t)sA * 1024 + hoff);
    uint4 hB = *(const uint4*)(hb + (size_t)sB * 1024 + hoff);
    float aA = __expf(leaky(eA + r4h)) * rd;
    float aB = __expf(leaky(eB + r4h)) * rd;
    a0 = fmaf(aA, b2f((u16)(hA.x & 0xffff)), a0);
    a1 = fmaf(aA, b2f((u16)(hA.x >> 16)), a1);
    a2 = fmaf(aA, b2f((u16)(hA.y & 0xffff)), a2);
    a3 = fmaf(aA, b2f((u16)(hA.y >> 16)), a3);
    a4 = fmaf(aA, b2f((u16)(hA.z & 0xffff)), a4);
    a5 = fmaf(aA, b2f((u16)(hA.z >> 16)), a5);
    a6 = fmaf(aA, b2f((u16)(hA.w & 0xffff)), a6);
    a7 = fmaf(aA, b2f((u16)(hA.w >> 16)), a7);
    a0 = fmaf(aB, b2f((u16)(hB.x & 0xffff)), a0);
    a1 = fmaf(aB, b2f((u16)(hB.x >> 16)), a1);
    a2 = fmaf(aB, b2f((u16)(hB.y & 0xffff)), a2);
    a3 = fmaf(aB, b2f((u16)(hB.y >> 16)), a3);
    a4 = fmaf(aB, b2f((u16)(hB.z & 0xffff)), a4);
    a5 = fmaf(aB, b2f((u16)(hB.z >> 16)), a5);
    a6 = fmaf(aB, b2f((u16)(hB.w & 0xffff)), a6);
    a7 = fmaf(aB, b2f((u16)(hB.w >> 16)), a7);
  }
  if (i < end) {
    int s = perm[i];
    float eh = elr[(size_t)s * 32 + r4i];
    float a = __expf(leaky(eh + r4h)) * rd;
    uint4 hv = *(const uint4*)(hb + (size_t)s * 1024 + hoff);
    a0 = fmaf(a, b2f((u16)(hv.x & 0xffff)), a0);
    a1 = fmaf(a, b2f((u16)(hv.x >> 16)), a1);
    a2 = fmaf(a, b2f((u16)(hv.y & 0xffff)), a2);
    a3 = fmaf(a, b2f((u16)(hv.y >> 16)), a3);
    a4 = fmaf(a, b2f((u16)(hv.z & 0xffff)), a4);
    a5 = fmaf(a, b2f((u16)(hv.z >> 16)), a5);
    a6 = fmaf(a, b2f((u16)(hv.w & 0xffff)), a6);
    a7 = fmaf(a, b2f((u16)(hv.w >> 16)), a7);
  }
  a0 += __shfl_xor(a0, 32); a1 += __shfl_xor(a1, 32);
  a2 += __shfl_xor(a2, 32); a3 += __shfl_xor(a3, 32);
  a4 += __shfl_xor(a4, 32); a5 += __shfl_xor(a5, 32);
  a6 += __shfl_xor(a6, 32); a7 += __shfl_xor(a7, 32);
  if (lane < 32) {
    float* pp = &sacc[w][lane32 * 8];
    pp[0] = a0; pp[1] = a1; pp[2] = a2; pp[3] = a3;
    pp[4] = a4; pp[5] = a5; pp[6] = a6; pp[7] = a7;
  }
  __syncthreads();
  if (tid < 256) {
    float v = 0.f;
    #pragma unroll
    for (int ww = 0; ww < 8; ++ww) v += sacc[ww][tid];
    float o = 0.25f * v + b2f(loopo[(size_t)d * 256 + tid]) + loop_b[tid];
    out[(size_t)d * 256 + tid] = fmaxf(o, 0.f);
  }
}

// ---------------- launcher ----------------
extern "C" void kernel_launch(void* const* d_in, const int* in_sizes, int n_in,
                              void* d_out, int out_size, void* d_ws, size_t ws_size,
                              hipStream_t stream) {
  const float* x      = (const float*)d_in[0];
  const float* W      = (const float*)d_in[1];
  const float* attn_l = (const float*)d_in[2];
  const float* attn_r = (const float*)d_in[3];
  const float* loop_w = (const float*)d_in[4];
  const float* loop_b = (const float*)d_in[5];
  const int* edge_src = (const int*)d_in[6];
  const int* edge_dst = (const int*)d_in[7];
  float* out = (float*)d_out;

  char* wsp = (char*)d_ws;
  size_t off = 0;
  auto alloc = [&](size_t bytes) -> char* {
    char* p = wsp + off;
    off = (off + bytes + 255) & ~(size_t)255;
    return p;
  };
  u16* xb      = (u16*)alloc((size_t)NSRC * 256 * 2);
  u16* Wt      = (u16*)alloc((size_t)1408 * 256 * 2);
  float* elr   = (float*)alloc((size_t)NSRC * 32 * 4);
  u16* loopo   = (u16*)alloc((size_t)NDST * 256 * 2);
  int* counts  = (int*)alloc((size_t)NREL * NDST * 4);
  int* offs    = (int*)alloc((size_t)(NREL * NDST + 1) * 4);
  int* cursor  = (int*)alloc((size_t)NREL * NDST * 4);
  int* btot    = (int*)alloc(64 * 4);
  int* carry   = (int*)alloc(64 * 4);
  int* perm    = (int*)alloc((size_t)NREL * NEDGE * 4);
  u16* hb      = (u16*)alloc((size_t)NSRC * 1024 * 2);  // total ~143.7 MB

  // conversions / weight prep
  cvtx_k<<<NSRC * 256 / 4 / 256, 256, 0, stream>>>(x, xb);
  cvtw_k<<<1280, 256, 0, stream>>>(W, loop_w, Wt);
  wa_k<<<128, 256, 0, stream>>>(W, attn_l, attn_r, Wt + (size_t)1280 * 256);

  // CSR (all relations)
  hipMemsetAsync(counts, 0, (size_t)NREL * NDST * 4, stream);
  const int EB = (NREL * NEDGE + 255) / 256;
  hist_k<<<EB, 256, 0, stream>>>(edge_dst, counts);
  scanA_k<<<40, 1024, 0, stream>>>(counts, offs, btot);
  scanB_k<<<1, 64, 0, stream>>>(btot, carry);
  scanC_k<<<40, 1024, 0, stream>>>(offs, carry, cursor);
  scatter_k<<<EB, 256, 0, stream>>>(edge_src, edge_dst, cursor, perm);

  // fused GEMM: hb | loopo | elr in one pass
  gemm_k<<<dim3(11, (NSRC + 127) / 128), 256, 0, stream>>>(xb, Wt, hb, loopo, elr);

  // fused softmax + aggregation + epilogue
  agg_k<<<NDST, 512, 0, stream>>>(hb, offs, perm, elr, loopo, loop_b, out);
}